// Round 5
// baseline (728.548 us; speedup 1.0000x reference)
//
#include <hip/hip_runtime.h>
#include <stdint.h>

// Problem constants: N=262144 rows, C=256 channels, K=256 codes.
#define CCH 256
#define KK  256

typedef int   i32x4 __attribute__((ext_vector_type(4)));
typedef float f32x4 __attribute__((ext_vector_type(4)));
typedef unsigned short u16x4 __attribute__((ext_vector_type(4)));
typedef unsigned short u16x8 __attribute__((ext_vector_type(8)));

// ---------------------------------------------------------------------------
// K0: compress white_table int32 -> uint8.
// ---------------------------------------------------------------------------
__global__ __launch_bounds__(256) void compress_table_kernel(
    const int4* __restrict__ t, uchar4* __restrict__ o, int n4) {
  int i = blockIdx.x * 256 + threadIdx.x;
  if (i < n4) {
    int4 v = t[i];
    o[i] = make_uchar4((unsigned char)v.x, (unsigned char)v.y,
                       (unsigned char)v.z, (unsigned char)v.w);
  }
}

// ---------------------------------------------------------------------------
// K1: transpose + pack, register-double-buffered across raw barriers.
// L,R [N,C] i32 -> LRtT tile-major [nslice/32][C][32] u16 = (l<<8)|r.
// Per block: T=8 tiles of 32 rows x 256 ch.  Tile t+1's 16 int4 loads are
// issued BEFORE the lgkmcnt-only barrier (no vmcnt drain -> loads stay in
// flight through the whole store phase).  Stores: 16 KB contiguous per tile.
// LDS: 32x260 u16 = 16.6 KB.  Phase-A writes row-contiguous (2-way, free);
// phase-B reads 64 consecutive channels per wave (conflict-free).
// ---------------------------------------------------------------------------
__global__ __launch_bounds__(256, 3) void transpose_pack_kernel(
    const i32x4* __restrict__ L4, const i32x4* __restrict__ R4,
    unsigned short* __restrict__ LRtT, int n0_base, int nslice) {
  __shared__ unsigned short tile[32 * 260];
  const int T     = 8;
  const int tile0 = blockIdx.x * T;          // slice-local tile index
  const int tid   = threadIdx.x;
  const int w     = tid >> 6;                // wave 0..3 -> row sub
  const int lq    = tid & 63;                // int4 quad within row

  i32x4 Lb[8], Rb[8];
  // Prologue: load tile0 into registers.
  {
    const size_t rowbase = (size_t)(n0_base + tile0 * 32);
#pragma unroll
    for (int p = 0; p < 8; ++p) {
      const size_t gi = (rowbase + p * 4 + w) * 64 + lq;
      Lb[p] = L4[gi];
      Rb[p] = R4[gi];
    }
  }

#pragma unroll 1
  for (int t = 0; t < T; ++t) {
    // Phase A: pack current tile's registers -> LDS.
#pragma unroll
    for (int p = 0; p < 8; ++p) {
      u16x4 pk;
      pk[0] = (unsigned short)((Lb[p][0] << 8) | Rb[p][0]);
      pk[1] = (unsigned short)((Lb[p][1] << 8) | Rb[p][1]);
      pk[2] = (unsigned short)((Lb[p][2] << 8) | Rb[p][2]);
      pk[3] = (unsigned short)((Lb[p][3] << 8) | Rb[p][3]);
      *(u16x4*)&tile[(p * 4 + w) * 260 + lq * 4] = pk;
    }
    // Issue next tile's loads (in flight across both barriers below).
    if (t + 1 < T) {
      const size_t rowbase = (size_t)(n0_base + (tile0 + t + 1) * 32);
#pragma unroll
      for (int p = 0; p < 8; ++p) {
        const size_t gi = (rowbase + p * 4 + w) * 64 + lq;
        Lb[p] = L4[gi];
        Rb[p] = R4[gi];
      }
    }
    // LDS-only barrier: wait ds_writes, do NOT drain vmcnt.
    asm volatile("s_waitcnt lgkmcnt(0)" ::: "memory");
    __builtin_amdgcn_s_barrier();

    // Phase B: thread owns channel tid; read its 32-row column, store 64 B.
    {
      unsigned short col[32];
#pragma unroll
      for (int r = 0; r < 32; ++r) col[r] = tile[r * 260 + tid];
      u16x8 s0, s1, s2, s3;
#pragma unroll
      for (int j = 0; j < 8; ++j) {
        s0[j] = col[j];
        s1[j] = col[8 + j];
        s2[j] = col[16 + j];
        s3[j] = col[24 + j];
      }
      unsigned short* dst = LRtT + ((size_t)(tile0 + t) * CCH + tid) * 32;
      *(u16x8*)(dst + 0)  = s0;
      *(u16x8*)(dst + 8)  = s1;
      *(u16x8*)(dst + 16) = s2;
      *(u16x8*)(dst + 24) = s3;
    }
    // Protect LDS reuse next iteration; still no vmcnt drain.
    asm volatile("s_waitcnt lgkmcnt(0)" ::: "memory");
    __builtin_amdgcn_s_barrier();
  }
}

// ---------------------------------------------------------------------------
// K2: per-channel code gather, 64 KB table in LDS, 512 threads, 2 blocks/CU.
// Input from tile-major LRtT: per instr a wave reads 16 full 64-B lines.
// All 8 input loads issued BEFORE table staging (latency overlap).
// blockIdx&255 = channel -> all of a channel's blocks on one XCD.
// ---------------------------------------------------------------------------
__global__ __launch_bounds__(512, 4) void code_gather_kernel(
    const unsigned short* __restrict__ LRtT, const unsigned char* __restrict__ tab8,
    unsigned char* __restrict__ codes, int nslice) {
  __shared__ unsigned char tabs[KK * KK];  // 64 KB
  const int c   = blockIdx.x & (CCH - 1);
  const int sub = blockIdx.x >> 8;
  const int tid = threadIdx.x;
  const int tbase = sub * 1024;            // first 32-row tile of this block

  u16x8 v[8];
#pragma unroll
  for (int i = 0; i < 8; ++i) {
    const size_t a =
        ((size_t)(tbase + i * 128 + (tid >> 2)) * CCH + c) * 32 + (tid & 3) * 8;
    v[i] = *(const u16x8*)(LRtT + a);
  }
  {
    const int4* src = (const int4*)(tab8 + (size_t)c * (KK * KK));
    int4* dst = (int4*)tabs;
#pragma unroll
    for (int i = 0; i < 8; ++i) dst[i * 512 + tid] = src[i * 512 + tid];
  }
  __syncthreads();

  uint2* outp = (uint2*)(codes + (size_t)c * nslice + (size_t)sub * 32768);
#pragma unroll
  for (int i = 0; i < 8; ++i) {
    unsigned lo = (unsigned)tabs[v[i][0]] | ((unsigned)tabs[v[i][1]] << 8) |
                  ((unsigned)tabs[v[i][2]] << 16) | ((unsigned)tabs[v[i][3]] << 24);
    unsigned hi = (unsigned)tabs[v[i][4]] | ((unsigned)tabs[v[i][5]] << 8) |
                  ((unsigned)tabs[v[i][6]] << 16) | ((unsigned)tabs[v[i][7]] << 24);
    outp[i * 512 + tid] = make_uint2(lo, hi);
  }
}

// ---------------------------------------------------------------------------
// K3: codebook + transpose back.  codes [C,nslice] u8 -> out [N,C] f32.
// Tile 256n x 32ch; LDS = 32 KB codebook + 8.5 KB pitched code tile
// -> 3 blocks/CU (vs 1 before).  Thread = (4-ch quad, 4-row group): 4 ctile
// dword reads -> 16 codes -> 16 gathers -> 4 x f32x4 NT stores (128-B
// segments, 8 cg-blocks adjacent in blockIdx fill each 1 KB row on
// different XCDs).
// ---------------------------------------------------------------------------
__global__ __launch_bounds__(512, 6) void codebook_transpose_kernel(
    const unsigned char* __restrict__ codes, const float* __restrict__ cb,
    float* __restrict__ out, int n0_base, int nslice) {
  __shared__ float    cbs[32 * KK];   // 32 KB
  __shared__ unsigned ctd[32 * 65];   // 8.5 KB, pitch 65 dwords
  const int cg = blockIdx.x & 7;
  const int tn = blockIdx.x >> 3;
  const int c0 = cg * 32;
  const int tid = threadIdx.x;

  {
    const f32x4* cbg = (const f32x4*)(cb + (size_t)c0 * KK);
    f32x4* cbl = (f32x4*)cbs;
#pragma unroll
    for (int i = 0; i < 4; ++i) cbl[i * 512 + tid] = cbg[i * 512 + tid];
  }
  {
    const int cc = tid >> 4;  // 0..31
    const int s  = tid & 15;  // 0..15
    const uint4 val = *(const uint4*)(codes + (size_t)(c0 + cc) * nslice +
                                      (size_t)tn * 256 + s * 16);
    const int d0 = cc * 65 + s * 4;
    ctd[d0 + 0] = val.x;
    ctd[d0 + 1] = val.y;
    ctd[d0 + 2] = val.z;
    ctd[d0 + 3] = val.w;
  }
  __syncthreads();

  const int cq = tid & 7;   // channel quad 0..7
  const int nb = tid >> 3;  // 0..63 (4-row group)
  const unsigned cw0 = ctd[(cq * 4 + 0) * 65 + nb];
  const unsigned cw1 = ctd[(cq * 4 + 1) * 65 + nb];
  const unsigned cw2 = ctd[(cq * 4 + 2) * 65 + nb];
  const unsigned cw3 = ctd[(cq * 4 + 3) * 65 + nb];
  const float* b0 = cbs + (cq * 4 + 0) * KK;
  const float* b1 = cbs + (cq * 4 + 1) * KK;
  const float* b2 = cbs + (cq * 4 + 2) * KK;
  const float* b3 = cbs + (cq * 4 + 3) * KK;
  float* ob = out + (size_t)(n0_base + tn * 256 + nb * 4) * CCH + c0 + cq * 4;
#pragma unroll
  for (int k = 0; k < 4; ++k) {
    f32x4 o;
    o[0] = b0[(cw0 >> (8 * k)) & 255u];
    o[1] = b1[(cw1 >> (8 * k)) & 255u];
    o[2] = b2[(cw2 >> (8 * k)) & 255u];
    o[3] = b3[(cw3 >> (8 * k)) & 255u];
    __builtin_nontemporal_store(o, (f32x4*)(ob + (size_t)k * CCH));
  }
}

// ---------------------------------------------------------------------------
// Fallback: TA-path gather, used only if workspace is tiny.
// ---------------------------------------------------------------------------
#define ROWS_PER_BLOCK 512
#define NGROUPS 16
#define GCH (CCH / NGROUPS)

template <typename TabT>
__global__ __launch_bounds__(256, 8) void gather_kernel(
    const i32x4* __restrict__ left, const i32x4* __restrict__ right,
    const TabT* __restrict__ tab, const float* __restrict__ cb,
    f32x4* __restrict__ out, int nrows) {
  __shared__ float cbs[GCH * KK];
  const int g     = blockIdx.x & (NGROUPS - 1);
  const int chunk = blockIdx.x / NGROUPS;
  const int q     = threadIdx.x & 3;
  const int rsub  = threadIdx.x >> 2;
  {
    const f32x4* cbg = (const f32x4*)(cb + (size_t)(g * GCH) * KK);
    f32x4* cbl = (f32x4*)cbs;
#pragma unroll
    for (int i = 0; i < 4; ++i) cbl[threadIdx.x + i * 256] = cbg[threadIdx.x + i * 256];
  }
  __syncthreads();
  const int cbase  = g * GCH + q * 4;
  const TabT* t0   = tab + (size_t)cbase * (KK * KK);
  const int vecoff = g * 4 + q;
  const float* cq  = cbs + (q * 4) * KK;
  const int rbase = chunk * ROWS_PER_BLOCK;
#pragma unroll
  for (int it = 0; it < ROWS_PER_BLOCK / 32; ++it) {
    const int r0 = rbase + it * 32 + rsub;
    if (r0 >= nrows) break;
    const unsigned v0 = (unsigned)r0 * 64u + (unsigned)vecoff;
    i32x4 L0 = left[v0];
    i32x4 R0 = right[v0];
    unsigned c0 = (unsigned)t0[          (unsigned)(L0[0] * KK + R0[0])];
    unsigned c1 = (unsigned)t0[ 65536u + (unsigned)(L0[1] * KK + R0[1])];
    unsigned c2 = (unsigned)t0[131072u + (unsigned)(L0[2] * KK + R0[2])];
    unsigned c3 = (unsigned)t0[196608u + (unsigned)(L0[3] * KK + R0[3])];
    f32x4 o;
    o[0] = cq[       c0];
    o[1] = cq[KK   + c1];
    o[2] = cq[2*KK + c2];
    o[3] = cq[3*KK + c3];
    out[v0] = o;
  }
}

extern "C" void kernel_launch(void* const* d_in, const int* in_sizes, int n_in,
                              void* d_out, int out_size, void* d_ws, size_t ws_size,
                              hipStream_t stream) {
  const int*   left  = (const int*)d_in[0];
  const int*   right = (const int*)d_in[1];
  const int*   wt    = (const int*)d_in[2];   // [C, K, K] int32
  const float* cb    = (const float*)d_in[3]; // [C, K] float32
  float* out = (float*)d_out;

  const int nrows = in_sizes[0] / CCH;        // 262144
  const int tab_elems = CCH * KK * KK;        // 16,777,216
  const size_t tab_bytes = (size_t)tab_elems; // u8 table = 16 MB

  // Pick smallest slicing S whose workspace fits:
  //   need = 16 MB table + 512*nslice (LRtT u16) + 256*nslice (codes u8)
  // Kernel divisibility requires nslice % 32768 == 0.
  int S = 0;
  for (int s = 1; s <= 8; s <<= 1) {
    if (nrows % (s * 32768)) continue;
    size_t need = tab_bytes + (size_t)768 * (size_t)(nrows / s);
    if (need <= ws_size) { S = s; break; }
  }

  if (S) {
    unsigned char* tab8 = (unsigned char*)d_ws;
    int n4 = tab_elems / 4;
    compress_table_kernel<<<n4 / 256, 256, 0, stream>>>(
        (const int4*)wt, (uchar4*)tab8, n4);

    const int nslice = nrows / S;
    unsigned short* LRtT = (unsigned short*)((char*)d_ws + tab_bytes);
    unsigned char* codes = (unsigned char*)d_ws + tab_bytes + (size_t)512 * nslice;

    for (int h = 0; h < S; ++h) {
      const int n0 = h * nslice;
      transpose_pack_kernel<<<nslice / 256, 256, 0, stream>>>(
          (const i32x4*)left, (const i32x4*)right, LRtT, n0, nslice);
      code_gather_kernel<<<(nslice / 32768) * CCH, 512, 0, stream>>>(
          LRtT, tab8, codes, nslice);
      codebook_transpose_kernel<<<(nslice / 256) * 8, 512, 0, stream>>>(
          codes, cb, out, n0, nslice);
    }
  } else if (ws_size >= tab_bytes) {
    unsigned char* tab8 = (unsigned char*)d_ws;
    int n4 = tab_elems / 4;
    compress_table_kernel<<<n4 / 256, 256, 0, stream>>>(
        (const int4*)wt, (uchar4*)tab8, n4);
    const int blocks = ((nrows + ROWS_PER_BLOCK - 1) / ROWS_PER_BLOCK) * NGROUPS;
    gather_kernel<unsigned char><<<blocks, 256, 0, stream>>>(
        (const i32x4*)left, (const i32x4*)right, tab8, cb, (f32x4*)out, nrows);
  } else {
    const int blocks = ((nrows + ROWS_PER_BLOCK - 1) / ROWS_PER_BLOCK) * NGROUPS;
    gather_kernel<int><<<blocks, 256, 0, stream>>>(
        (const i32x4*)left, (const i32x4*)right, wt, cb, (f32x4*)out, nrows);
  }
}